// Round 18
// baseline (127.055 us; speedup 1.0000x reference)
//
#include <hip/hip_runtime.h>
#include <hip/hip_bf16.h>

#define IN_CH 128
#define HID 64
#define OUT_CH 16

#define G_SH 7
#define G_SZ 128          // dst nodes per bucket
#define NBK_MAX 800       // max buckets (n <= 102400)
#define CHUNK 2048        // edges per bucketing block (r18: 4096->2048, 2x blocks)
#define CAP 4096          // fixed capacity per bucket (mean 2048, sigma ~45)

#define XROW 136          // padded LDS row length in bf16 (128 + 8)

typedef short bf16x8 __attribute__((ext_vector_type(8)));
typedef float f32x4 __attribute__((ext_vector_type(4)));

__device__ __forceinline__ float bf_lo(unsigned w) { return __uint_as_float(w << 16); }
__device__ __forceinline__ float bf_hi(unsigned w) { return __uint_as_float(w & 0xffff0000u); }

__device__ __forceinline__ unsigned short f2bf(float f) {
    __hip_bfloat16 h = __float2bfloat16(f);
    unsigned short u;
    __builtin_memcpy(&u, &h, 2);
    return u;
}

__device__ __forceinline__ unsigned pack_bf2(float lo, float hi) {
    return ((unsigned)f2bf(hi) << 16) | (unsigned)f2bf(lo);
}

// ---------------- setup: bucket cursors + W1->bf16 transposed ----------------

__global__ void k_setup(int* __restrict__ bcur, int nb,
                        const float* __restrict__ W, unsigned short* __restrict__ wt) {
    int i = blockIdx.x * blockDim.x + threadIdx.x;
    if (i < nb) bcur[i] = i * CAP;
    if (i < IN_CH * HID) {
        int ch = i >> 7, k = i & 127;
        wt[ch * IN_CH + k] = f2bf(W[k * HID + ch]);
    }
}

// ---------------- edge bucketing (coarse sort by dst>>7) ----------------
// Logic frozen at round-11 (known good); only CHUNK parameter changed.
// packed word: (d_local << 17) | src
__global__ __launch_bounds__(256) void k_bucket(const int* __restrict__ ei,
                                                int* __restrict__ bcursor,
                                                int* __restrict__ packed, int E, int nb) {
    __shared__ int hcnt[NBK_MAX];
    __shared__ int hoff[NBK_MAX];
    __shared__ int hbase[NBK_MAX];
    __shared__ int hcur[NBK_MAX];
    __shared__ int stage[CHUNK];
    __shared__ unsigned short sbk[CHUNK];
    __shared__ int scan_s[256];
    __shared__ int sh_carry;

    int tid = threadIdx.x;
    int base = blockIdx.x * CHUNK;
    int cnt = E - base;
    if (cnt > CHUNK) cnt = CHUNK;
    for (int t = tid; t < nb; t += 256) { hcnt[t] = 0; hcur[t] = 0; }
    if (tid == 0) sh_carry = 0;
    __syncthreads();

    int mp[CHUNK / 256], mb[CHUNK / 256];
#pragma unroll
    for (int k = 0; k < CHUNK / 256; ++k) {
        int idx = base + k * 256 + tid;
        int p = 0, b = -1;
        if (idx < E) {
            int s = ei[idx];
            int d = ei[E + idx];
            b = d >> G_SH;
            p = ((d & (G_SZ - 1)) << 17) | s;
            atomicAdd(&hcnt[b], 1);
        }
        mp[k] = p; mb[k] = b;
    }
    __syncthreads();

    // exclusive scan of hcnt -> hoff
    for (int s0 = 0; s0 < nb; s0 += 256) {
        int i = s0 + tid;
        int v = (i < nb) ? hcnt[i] : 0;
        scan_s[tid] = v;
        __syncthreads();
        for (int off = 1; off < 256; off <<= 1) {
            int t = (tid >= off) ? scan_s[tid - off] : 0;
            __syncthreads();
            scan_s[tid] += t;
            __syncthreads();
        }
        if (i < nb) hoff[i] = sh_carry + scan_s[tid] - v;
        __syncthreads();
        if (tid == 255) sh_carry += scan_s[255];
        __syncthreads();
    }

    // reserve space in fixed-capacity bucket regions
    for (int t = tid; t < nb; t += 256)
        if (hcnt[t] > 0) hbase[t] = atomicAdd(&bcursor[t], hcnt[t]);
    __syncthreads();

    // LDS scatter into bucket-ordered staging
#pragma unroll
    for (int k = 0; k < CHUNK / 256; ++k) {
        int b = mb[k];
        if (b >= 0) {
            int slot = hoff[b] + atomicAdd(&hcur[b], 1);
            stage[slot] = mp[k];
            sbk[slot] = (unsigned short)b;
        }
    }
    __syncthreads();

    // coalesced run write-out
    for (int i = tid; i < cnt; i += 256) {
        int b = sbk[i];
        packed[hbase[b] + (i - hoff[b])] = stage[i];
    }
}

// ---- per-bucket fine counting sort; emits rowptr/counts/dinv per node ----

__global__ __launch_bounds__(256) void k_sortbkt(const int* __restrict__ bcursor,
                                                 int* __restrict__ packed,
                                                 int* __restrict__ rowptr,
                                                 int* __restrict__ counts,
                                                 float* __restrict__ dinv, int n) {
    __shared__ int sc[G_SZ];
    __shared__ int lcur[G_SZ];
    __shared__ int stage[CAP];
    __shared__ int sorted_[CAP];

    int tid = threadIdx.x;
    int bkt = blockIdx.x;
    int d0 = bkt << G_SH;
    int base = bkt * CAP;
    int L = bcursor[bkt] - base;

    if (tid < G_SZ) sc[tid] = 0;
    __syncthreads();
    for (int i = tid; i < L; i += 256) {
        int p = packed[base + i];
        stage[i] = p;
        atomicAdd(&sc[p >> 17], 1);
    }
    __syncthreads();
    int v = (tid < G_SZ) ? sc[tid] : 0;
    for (int off = 1; off < G_SZ; off <<= 1) {
        int t = (tid < G_SZ && tid >= off) ? sc[tid - off] : 0;
        __syncthreads();
        if (tid < G_SZ) sc[tid] += t;
        __syncthreads();
    }
    if (tid < G_SZ) {
        int excl = sc[tid] - v;
        lcur[tid] = excl;
        int d = d0 + tid;
        if (d < n) {
            rowptr[d] = base + excl;
            counts[d] = v;
            dinv[d] = rsqrtf((float)(v + 1));  // +1 = self-loop
        }
    }
    __syncthreads();
    for (int i = tid; i < L; i += 256) {
        int p = stage[i];
        int pos = atomicAdd(&lcur[p >> 17], 1);
        sorted_[pos] = p & 0x1FFFF;
    }
    __syncthreads();
    for (int i = tid; i < L; i += 256) packed[base + i] = sorted_[i];
}

// ---------------- layer 1: MFMA GEMM ----------------

__global__ __launch_bounds__(256) void k_gemm1(const float* __restrict__ x,
                                               const unsigned short* __restrict__ wt,
                                               const float* __restrict__ dinv,
                                               __hip_bfloat16* __restrict__ xlp, int n) {
    __shared__ unsigned short sx[64 * XROW];
    __shared__ unsigned short sw[64 * XROW];
    int tid = threadIdx.x;
    int node0 = blockIdx.x * 64;

    for (int i = tid; i < 64 * 16; i += 256) {
        int row = i >> 4, kk = i & 15;
        uint4 v = ((const uint4*)wt)[i];
        *(uint4*)&sw[row * XROW + kk * 8] = v;
    }
    for (int i = tid; i < 64 * 32; i += 256) {
        int row = i >> 5, k4 = i & 31;
        int node = node0 + row;
        float4 v = (node < n) ? ((const float4*)(x + (size_t)node * IN_CH))[k4]
                              : make_float4(0.f, 0.f, 0.f, 0.f);
        uint2 p;
        p.x = pack_bf2(v.x, v.y);
        p.y = pack_bf2(v.z, v.w);
        *(uint2*)&sx[row * XROW + k4 * 4] = p;
    }
    __syncthreads();

    int w = tid >> 6, lane = tid & 63;
    int lrow = lane & 15, lg = lane >> 4;
    f32x4 acc0 = {0.f, 0.f, 0.f, 0.f}, acc1 = {0.f, 0.f, 0.f, 0.f};
    f32x4 acc2 = {0.f, 0.f, 0.f, 0.f}, acc3 = {0.f, 0.f, 0.f, 0.f};
    const unsigned short* ax = &sx[(16 * w + lrow) * XROW + lg * 8];
#pragma unroll
    for (int k0 = 0; k0 < IN_CH; k0 += 32) {
        bf16x8 a = *(const bf16x8*)&ax[k0];
        bf16x8 b0 = *(const bf16x8*)&sw[(lrow) * XROW + lg * 8 + k0];
        bf16x8 b1 = *(const bf16x8*)&sw[(16 + lrow) * XROW + lg * 8 + k0];
        bf16x8 b2 = *(const bf16x8*)&sw[(32 + lrow) * XROW + lg * 8 + k0];
        bf16x8 b3 = *(const bf16x8*)&sw[(48 + lrow) * XROW + lg * 8 + k0];
        acc0 = __builtin_amdgcn_mfma_f32_16x16x32_bf16(a, b0, acc0, 0, 0, 0);
        acc1 = __builtin_amdgcn_mfma_f32_16x16x32_bf16(a, b1, acc1, 0, 0, 0);
        acc2 = __builtin_amdgcn_mfma_f32_16x16x32_bf16(a, b2, acc2, 0, 0, 0);
        acc3 = __builtin_amdgcn_mfma_f32_16x16x32_bf16(a, b3, acc3, 0, 0, 0);
    }
#pragma unroll
    for (int r = 0; r < 4; ++r) {
        int node = node0 + 16 * w + lg * 4 + r;
        if (node < n) {
            float dd = dinv[node];
            __hip_bfloat16* o = xlp + (size_t)node * HID + lrow;
            o[0]  = __float2bfloat16(dd * acc0[r]);
            o[16] = __float2bfloat16(dd * acc1[r]);
            o[32] = __float2bfloat16(dd * acc2[r]);
            o[48] = __float2bfloat16(dd * acc3[r]);
        }
    }
}

// ---------------- fused agg1 + gemm2, dwordx4 gathers (round-16 verbatim) ----
// 32-lane group per dst. h = cl>>3 picks 1 of 4 edges per instruction;
// sub = cl&7 picks a 16B slice of the 128B xlp row.

__global__ __launch_bounds__(256) void k_agg1f(const int* __restrict__ rowptr,
                                               const int* __restrict__ counts,
                                               const int* __restrict__ esrc,
                                               const float* __restrict__ dinv,
                                               const __hip_bfloat16* __restrict__ xlp,
                                               const float* __restrict__ b1,
                                               const float* __restrict__ W2,
                                               __hip_bfloat16* __restrict__ hlp, int n) {
    __shared__ float sW2[HID * OUT_CH];  // 4 KB
    __shared__ float sh[8][HID];         // 2 KB
    int tid = threadIdx.x;
    for (int i = tid; i < HID * OUT_CH; i += 256) sW2[i] = W2[i];
    __syncthreads();  // sW2 visible to all waves

    int g = tid >> 5;
    int cl = tid & 31;
    int d = blockIdx.x * 8 + g;
    if (d >= n) return;
    int h = cl >> 3;     // edge slot within quad
    int sub = cl & 7;    // 16B slice -> channels 8*sub .. 8*sub+7
    int j0 = rowptr[d];
    int cnt = counts[d];
    float dd = dinv[d];

    float a0 = 0.f, a1 = 0.f, a2 = 0.f, a3 = 0.f;
    float a4 = 0.f, a5 = 0.f, a6 = 0.f, a7 = 0.f;
    const uint4 zero4 = make_uint4(0u, 0u, 0u, 0u);
    for (int t = 0; t < cnt; t += 16) {
        int e0 = t + h, e1 = t + 4 + h, e2 = t + 8 + h, e3 = t + 12 + h;
        // over-reads stay inside the CAP-padded bucket region; mask below
        int s0 = esrc[j0 + e0] & 0x1FFFF;
        int s1 = esrc[j0 + e1] & 0x1FFFF;
        int s2 = esrc[j0 + e2] & 0x1FFFF;
        int s3 = esrc[j0 + e3] & 0x1FFFF;
        uint4 w0 = ((const uint4*)(xlp + (size_t)s0 * HID))[sub];
        uint4 w1 = ((const uint4*)(xlp + (size_t)s1 * HID))[sub];
        uint4 w2 = ((const uint4*)(xlp + (size_t)s2 * HID))[sub];
        uint4 w3 = ((const uint4*)(xlp + (size_t)s3 * HID))[sub];
        if (e0 >= cnt) w0 = zero4;
        if (e1 >= cnt) w1 = zero4;
        if (e2 >= cnt) w2 = zero4;
        if (e3 >= cnt) w3 = zero4;
        a0 += (bf_lo(w0.x) + bf_lo(w1.x)) + (bf_lo(w2.x) + bf_lo(w3.x));
        a1 += (bf_hi(w0.x) + bf_hi(w1.x)) + (bf_hi(w2.x) + bf_hi(w3.x));
        a2 += (bf_lo(w0.y) + bf_lo(w1.y)) + (bf_lo(w2.y) + bf_lo(w3.y));
        a3 += (bf_hi(w0.y) + bf_hi(w1.y)) + (bf_hi(w2.y) + bf_hi(w3.y));
        a4 += (bf_lo(w0.z) + bf_lo(w1.z)) + (bf_lo(w2.z) + bf_lo(w3.z));
        a5 += (bf_hi(w0.z) + bf_hi(w1.z)) + (bf_hi(w2.z) + bf_hi(w3.z));
        a6 += (bf_lo(w0.w) + bf_lo(w1.w)) + (bf_lo(w2.w) + bf_lo(w3.w));
        a7 += (bf_hi(w0.w) + bf_hi(w1.w)) + (bf_hi(w2.w) + bf_hi(w3.w));
    }
    // combine the 4 h-subgroups (lanes sharing `sub`)
    a0 += __shfl_xor(a0, 8);  a0 += __shfl_xor(a0, 16);
    a1 += __shfl_xor(a1, 8);  a1 += __shfl_xor(a1, 16);
    a2 += __shfl_xor(a2, 8);  a2 += __shfl_xor(a2, 16);
    a3 += __shfl_xor(a3, 8);  a3 += __shfl_xor(a3, 16);
    a4 += __shfl_xor(a4, 8);  a4 += __shfl_xor(a4, 16);
    a5 += __shfl_xor(a5, 8);  a5 += __shfl_xor(a5, 16);
    a6 += __shfl_xor(a6, 8);  a6 += __shfl_xor(a6, 16);
    a7 += __shfl_xor(a7, 8);  a7 += __shfl_xor(a7, 16);

    uint4 wsv = ((const uint4*)(xlp + (size_t)d * HID))[sub];  // self-loop
    float4 bA = *(const float4*)&b1[8 * sub];
    float4 bB = *(const float4*)&b1[8 * sub + 4];
    float v0 = fmaxf(dd * (a0 + bf_lo(wsv.x)) + bA.x, 0.f);
    float v1 = fmaxf(dd * (a1 + bf_hi(wsv.x)) + bA.y, 0.f);
    float v2 = fmaxf(dd * (a2 + bf_lo(wsv.y)) + bA.z, 0.f);
    float v3 = fmaxf(dd * (a3 + bf_hi(wsv.y)) + bA.w, 0.f);
    float v4 = fmaxf(dd * (a4 + bf_lo(wsv.z)) + bB.x, 0.f);
    float v5 = fmaxf(dd * (a5 + bf_hi(wsv.z)) + bB.y, 0.f);
    float v6 = fmaxf(dd * (a6 + bf_lo(wsv.w)) + bB.z, 0.f);
    float v7 = fmaxf(dd * (a7 + bf_hi(wsv.w)) + bB.w, 0.f);
    // group-private staging: h==0 lanes write all 64 channels;
    // same-wave write->read, SIMD program order (validated round 14)
    if (h == 0) {
        *(float4*)&sh[g][8 * sub]     = make_float4(v0, v1, v2, v3);
        *(float4*)&sh[g][8 * sub + 4] = make_float4(v4, v5, v6, v7);
    }

    int j = cl & 15, kh = cl >> 4;
    float acc = 0.f;
#pragma unroll 8
    for (int k = 0; k < 32; ++k) {
        int kk = kh * 32 + k;
        acc += sh[g][kk] * sW2[kk * OUT_CH + j];
    }
    acc += __shfl_xor(acc, 16);  // combine k-halves
    if (cl < 16)
        hlp[(size_t)d * OUT_CH + j] = __float2bfloat16(dd * acc);
}

// ---------------- layer 2 aggregation (round-16 verbatim) ----------------
// 8-lane group per dst. h = cl>>2 picks 1 of 2 edges; sub = cl&3 picks an
// 8B slice (4 ch) of the 32B hlp row.

__global__ __launch_bounds__(256) void k_agg2(const int* __restrict__ rowptr,
                                              const int* __restrict__ counts,
                                              const int* __restrict__ esrc,
                                              const float* __restrict__ dinv,
                                              const __hip_bfloat16* __restrict__ hlp,
                                              const float* __restrict__ b,
                                              float* __restrict__ out, int n) {
    int d = blockIdx.x * 32 + (threadIdx.x >> 3);
    if (d >= n) return;
    int cl = threadIdx.x & 7;
    int h = cl >> 2;     // edge slot within pair
    int sub = cl & 3;    // 8B slice -> channels 4*sub .. 4*sub+3
    int j0 = rowptr[d];
    int cnt = counts[d];
    float dd = dinv[d];

    float a0 = 0.f, a1 = 0.f, a2 = 0.f, a3 = 0.f;
    const uint2 zero2 = make_uint2(0u, 0u);
    for (int t = 0; t < cnt; t += 8) {
        int e0 = t + h, e1 = t + 2 + h, e2 = t + 4 + h, e3 = t + 6 + h;
        int s0 = esrc[j0 + e0] & 0x1FFFF;
        int s1 = esrc[j0 + e1] & 0x1FFFF;
        int s2 = esrc[j0 + e2] & 0x1FFFF;
        int s3 = esrc[j0 + e3] & 0x1FFFF;
        uint2 w0 = ((const uint2*)(hlp + (size_t)s0 * OUT_CH))[sub];
        uint2 w1 = ((const uint2*)(hlp + (size_t)s1 * OUT_CH))[sub];
        uint2 w2 = ((const uint2*)(hlp + (size_t)s2 * OUT_CH))[sub];
        uint2 w3 = ((const uint2*)(hlp + (size_t)s3 * OUT_CH))[sub];
        if (e0 >= cnt) w0 = zero2;
        if (e1 >= cnt) w1 = zero2;
        if (e2 >= cnt) w2 = zero2;
        if (e3 >= cnt) w3 = zero2;
        a0 += (bf_lo(w0.x) + bf_lo(w1.x)) + (bf_lo(w2.x) + bf_lo(w3.x));
        a1 += (bf_hi(w0.x) + bf_hi(w1.x)) + (bf_hi(w2.x) + bf_hi(w3.x));
        a2 += (bf_lo(w0.y) + bf_lo(w1.y)) + (bf_lo(w2.y) + bf_lo(w3.y));
        a3 += (bf_hi(w0.y) + bf_hi(w1.y)) + (bf_hi(w2.y) + bf_hi(w3.y));
    }
    // combine the 2 h-subgroups (lane ^ 4 stays within the 8-lane group)
    a0 += __shfl_xor(a0, 4);
    a1 += __shfl_xor(a1, 4);
    a2 += __shfl_xor(a2, 4);
    a3 += __shfl_xor(a3, 4);

    uint2 ws = ((const uint2*)(hlp + (size_t)d * OUT_CH))[sub];  // self-loop
    float4 bv = *(const float4*)&b[4 * sub];
    float v0 = dd * (a0 + bf_lo(ws.x)) + bv.x;
    float v1 = dd * (a1 + bf_hi(ws.x)) + bv.y;
    float v2 = dd * (a2 + bf_lo(ws.y)) + bv.z;
    float v3 = dd * (a3 + bf_hi(ws.y)) + bv.w;
    if (h == 0)
        ((float4*)(out + (size_t)d * OUT_CH))[sub] = make_float4(v0, v1, v2, v3);
}

extern "C" void kernel_launch(void* const* d_in, const int* in_sizes, int n_in,
                              void* d_out, int out_size, void* d_ws, size_t ws_size,
                              hipStream_t stream) {
    const float* x  = (const float*)d_in[0];
    const int* ei   = (const int*)d_in[1];   // int32 from harness
    const float* W1 = (const float*)d_in[2];
    const float* b1 = (const float*)d_in[3];
    const float* W2 = (const float*)d_in[4];
    const float* b2 = (const float*)d_in[5];
    float* out = (float*)d_out;

    const int n = in_sizes[0] / IN_CH;      // 100000
    const int E = in_sizes[1] / 2;          // 1600000
    const int nb = (n + G_SZ - 1) >> G_SH;  // 782 buckets
    const int nchunk = (E + CHUNK - 1) / CHUNK;  // 782 blocks at CHUNK=2048

    int* rowptr  = (int*)d_ws;
    int* counts  = rowptr + n;
    int* bcursor = counts + n;
    unsigned short* wtbf = (unsigned short*)(bcursor + 1024);  // 8192 shorts
    int* packed  = (int*)(wtbf + 8192);
    float* dinv  = (float*)(packed + (size_t)nb * CAP);
    __hip_bfloat16* xlp = (__hip_bfloat16*)(dinv + n);          // n*64 bf16 (16B-aligned)
    __hip_bfloat16* hlp = xlp + (size_t)n * HID;                // n*16 bf16 (separate)

    // setup + CSR build
    k_setup<<<(IN_CH * HID + 255) / 256, 256, 0, stream>>>(bcursor, nb, W1, wtbf);
    k_bucket<<<nchunk, 256, 0, stream>>>(ei, bcursor, packed, E, nb);
    k_sortbkt<<<nb, 256, 0, stream>>>(bcursor, packed, rowptr, counts, dinv, n);

    // layer 1 (+ fused layer-2 transform)
    k_gemm1<<<(n + 63) / 64, 256, 0, stream>>>(x, wtbf, dinv, xlp, n);
    k_agg1f<<<(n + 7) / 8, 256, 0, stream>>>(rowptr, counts, packed, dinv, xlp, b1, W2, hlp, n);

    // layer 2 aggregation
    k_agg2<<<(n + 31) / 32, 256, 0, stream>>>(rowptr, counts, packed, dinv, hlp, b2, out, n);
}

// Round 19
// 116.195 us; speedup vs baseline: 1.0935x; 1.0935x over previous
//
#include <hip/hip_runtime.h>
#include <hip/hip_bf16.h>

#define IN_CH 128
#define HID 64
#define OUT_CH 16

#define G_SH 7
#define G_SZ 128          // dst nodes per bucket
#define NBK_MAX 800       // max buckets (n <= 102400)
#define CHUNK 4096        // edges per bucketing block (r16 optimum; 2048 regressed)
#define CAP 4096          // fixed capacity per bucket (mean 2048, sigma ~45)

#define XROW 136          // padded LDS row length in bf16 (128 + 8)

typedef short bf16x8 __attribute__((ext_vector_type(8)));
typedef float f32x4 __attribute__((ext_vector_type(4)));

__device__ __forceinline__ float bf_lo(unsigned w) { return __uint_as_float(w << 16); }
__device__ __forceinline__ float bf_hi(unsigned w) { return __uint_as_float(w & 0xffff0000u); }

__device__ __forceinline__ unsigned short f2bf(float f) {
    __hip_bfloat16 h = __float2bfloat16(f);
    unsigned short u;
    __builtin_memcpy(&u, &h, 2);
    return u;
}

__device__ __forceinline__ unsigned pack_bf2(float lo, float hi) {
    return ((unsigned)f2bf(hi) << 16) | (unsigned)f2bf(lo);
}

// ---------------- setup: bucket cursors + W1->bf16 transposed ----------------

__global__ void k_setup(int* __restrict__ bcur, int nb,
                        const float* __restrict__ W, unsigned short* __restrict__ wt) {
    int i = blockIdx.x * blockDim.x + threadIdx.x;
    if (i < nb) bcur[i] = i * CAP;
    if (i < IN_CH * HID) {
        int ch = i >> 7, k = i & 127;
        wt[ch * IN_CH + k] = f2bf(W[k * HID + ch]);
    }
}

// ---------------- edge bucketing (coarse sort by dst>>7) ----------------
// ROUND-11 VERBATIM (known good, frozen). packed word: (d_local << 17) | src
__global__ __launch_bounds__(256) void k_bucket(const int* __restrict__ ei,
                                                int* __restrict__ bcursor,
                                                int* __restrict__ packed, int E, int nb) {
    __shared__ int hcnt[NBK_MAX];
    __shared__ int hoff[NBK_MAX];
    __shared__ int hbase[NBK_MAX];
    __shared__ int hcur[NBK_MAX];
    __shared__ int stage[CHUNK];
    __shared__ unsigned short sbk[CHUNK];
    __shared__ int scan_s[256];
    __shared__ int sh_carry;

    int tid = threadIdx.x;
    int base = blockIdx.x * CHUNK;
    int cnt = E - base;
    if (cnt > CHUNK) cnt = CHUNK;
    for (int t = tid; t < nb; t += 256) { hcnt[t] = 0; hcur[t] = 0; }
    if (tid == 0) sh_carry = 0;
    __syncthreads();

    int mp[CHUNK / 256], mb[CHUNK / 256];
#pragma unroll
    for (int k = 0; k < CHUNK / 256; ++k) {
        int idx = base + k * 256 + tid;
        int p = 0, b = -1;
        if (idx < E) {
            int s = ei[idx];
            int d = ei[E + idx];
            b = d >> G_SH;
            p = ((d & (G_SZ - 1)) << 17) | s;
            atomicAdd(&hcnt[b], 1);
        }
        mp[k] = p; mb[k] = b;
    }
    __syncthreads();

    // exclusive scan of hcnt -> hoff
    for (int s0 = 0; s0 < nb; s0 += 256) {
        int i = s0 + tid;
        int v = (i < nb) ? hcnt[i] : 0;
        scan_s[tid] = v;
        __syncthreads();
        for (int off = 1; off < 256; off <<= 1) {
            int t = (tid >= off) ? scan_s[tid - off] : 0;
            __syncthreads();
            scan_s[tid] += t;
            __syncthreads();
        }
        if (i < nb) hoff[i] = sh_carry + scan_s[tid] - v;
        __syncthreads();
        if (tid == 255) sh_carry += scan_s[255];
        __syncthreads();
    }

    // reserve space in fixed-capacity bucket regions
    for (int t = tid; t < nb; t += 256)
        if (hcnt[t] > 0) hbase[t] = atomicAdd(&bcursor[t], hcnt[t]);
    __syncthreads();

    // LDS scatter into bucket-ordered staging
#pragma unroll
    for (int k = 0; k < CHUNK / 256; ++k) {
        int b = mb[k];
        if (b >= 0) {
            int slot = hoff[b] + atomicAdd(&hcur[b], 1);
            stage[slot] = mp[k];
            sbk[slot] = (unsigned short)b;
        }
    }
    __syncthreads();

    // coalesced run write-out
    for (int i = tid; i < cnt; i += 256) {
        int b = sbk[i];
        packed[hbase[b] + (i - hoff[b])] = stage[i];
    }
}

// ---- per-bucket fine counting sort; emits rowptr/counts/dinv per node ----

__global__ __launch_bounds__(256) void k_sortbkt(const int* __restrict__ bcursor,
                                                 int* __restrict__ packed,
                                                 int* __restrict__ rowptr,
                                                 int* __restrict__ counts,
                                                 float* __restrict__ dinv, int n) {
    __shared__ int sc[G_SZ];
    __shared__ int lcur[G_SZ];
    __shared__ int stage[CAP];
    __shared__ int sorted_[CAP];

    int tid = threadIdx.x;
    int bkt = blockIdx.x;
    int d0 = bkt << G_SH;
    int base = bkt * CAP;
    int L = bcursor[bkt] - base;

    if (tid < G_SZ) sc[tid] = 0;
    __syncthreads();
    for (int i = tid; i < L; i += 256) {
        int p = packed[base + i];
        stage[i] = p;
        atomicAdd(&sc[p >> 17], 1);
    }
    __syncthreads();
    int v = (tid < G_SZ) ? sc[tid] : 0;
    for (int off = 1; off < G_SZ; off <<= 1) {
        int t = (tid < G_SZ && tid >= off) ? sc[tid - off] : 0;
        __syncthreads();
        if (tid < G_SZ) sc[tid] += t;
        __syncthreads();
    }
    if (tid < G_SZ) {
        int excl = sc[tid] - v;
        lcur[tid] = excl;
        int d = d0 + tid;
        if (d < n) {
            rowptr[d] = base + excl;
            counts[d] = v;
            dinv[d] = rsqrtf((float)(v + 1));  // +1 = self-loop
        }
    }
    __syncthreads();
    for (int i = tid; i < L; i += 256) {
        int p = stage[i];
        int pos = atomicAdd(&lcur[p >> 17], 1);
        sorted_[pos] = p & 0x1FFFF;
    }
    __syncthreads();
    for (int i = tid; i < L; i += 256) packed[base + i] = sorted_[i];
}

// ---------------- layer 1: MFMA GEMM ----------------

__global__ __launch_bounds__(256) void k_gemm1(const float* __restrict__ x,
                                               const unsigned short* __restrict__ wt,
                                               const float* __restrict__ dinv,
                                               __hip_bfloat16* __restrict__ xlp, int n) {
    __shared__ unsigned short sx[64 * XROW];
    __shared__ unsigned short sw[64 * XROW];
    int tid = threadIdx.x;
    int node0 = blockIdx.x * 64;

    for (int i = tid; i < 64 * 16; i += 256) {
        int row = i >> 4, kk = i & 15;
        uint4 v = ((const uint4*)wt)[i];
        *(uint4*)&sw[row * XROW + kk * 8] = v;
    }
    for (int i = tid; i < 64 * 32; i += 256) {
        int row = i >> 5, k4 = i & 31;
        int node = node0 + row;
        float4 v = (node < n) ? ((const float4*)(x + (size_t)node * IN_CH))[k4]
                              : make_float4(0.f, 0.f, 0.f, 0.f);
        uint2 p;
        p.x = pack_bf2(v.x, v.y);
        p.y = pack_bf2(v.z, v.w);
        *(uint2*)&sx[row * XROW + k4 * 4] = p;
    }
    __syncthreads();

    int w = tid >> 6, lane = tid & 63;
    int lrow = lane & 15, lg = lane >> 4;
    f32x4 acc0 = {0.f, 0.f, 0.f, 0.f}, acc1 = {0.f, 0.f, 0.f, 0.f};
    f32x4 acc2 = {0.f, 0.f, 0.f, 0.f}, acc3 = {0.f, 0.f, 0.f, 0.f};
    const unsigned short* ax = &sx[(16 * w + lrow) * XROW + lg * 8];
#pragma unroll
    for (int k0 = 0; k0 < IN_CH; k0 += 32) {
        bf16x8 a = *(const bf16x8*)&ax[k0];
        bf16x8 b0 = *(const bf16x8*)&sw[(lrow) * XROW + lg * 8 + k0];
        bf16x8 b1 = *(const bf16x8*)&sw[(16 + lrow) * XROW + lg * 8 + k0];
        bf16x8 b2 = *(const bf16x8*)&sw[(32 + lrow) * XROW + lg * 8 + k0];
        bf16x8 b3 = *(const bf16x8*)&sw[(48 + lrow) * XROW + lg * 8 + k0];
        acc0 = __builtin_amdgcn_mfma_f32_16x16x32_bf16(a, b0, acc0, 0, 0, 0);
        acc1 = __builtin_amdgcn_mfma_f32_16x16x32_bf16(a, b1, acc1, 0, 0, 0);
        acc2 = __builtin_amdgcn_mfma_f32_16x16x32_bf16(a, b2, acc2, 0, 0, 0);
        acc3 = __builtin_amdgcn_mfma_f32_16x16x32_bf16(a, b3, acc3, 0, 0, 0);
    }
#pragma unroll
    for (int r = 0; r < 4; ++r) {
        int node = node0 + 16 * w + lg * 4 + r;
        if (node < n) {
            float dd = dinv[node];
            __hip_bfloat16* o = xlp + (size_t)node * HID + lrow;
            o[0]  = __float2bfloat16(dd * acc0[r]);
            o[16] = __float2bfloat16(dd * acc1[r]);
            o[32] = __float2bfloat16(dd * acc2[r]);
            o[48] = __float2bfloat16(dd * acc3[r]);
        }
    }
}

// ---------------- fused agg1 + gemm2, dwordx4 gathers (r16 verbatim) ----
// 32-lane group per dst. h = cl>>3 picks 1 of 4 edges per instruction;
// sub = cl&7 picks a 16B slice of the 128B xlp row.

__global__ __launch_bounds__(256) void k_agg1f(const int* __restrict__ rowptr,
                                               const int* __restrict__ counts,
                                               const int* __restrict__ esrc,
                                               const float* __restrict__ dinv,
                                               const __hip_bfloat16* __restrict__ xlp,
                                               const float* __restrict__ b1,
                                               const float* __restrict__ W2,
                                               __hip_bfloat16* __restrict__ hlp, int n) {
    __shared__ float sW2[HID * OUT_CH];  // 4 KB
    __shared__ float sh[8][HID];         // 2 KB
    int tid = threadIdx.x;
    for (int i = tid; i < HID * OUT_CH; i += 256) sW2[i] = W2[i];
    __syncthreads();  // sW2 visible to all waves

    int g = tid >> 5;
    int cl = tid & 31;
    int d = blockIdx.x * 8 + g;
    if (d >= n) return;
    int h = cl >> 3;     // edge slot within quad
    int sub = cl & 7;    // 16B slice -> channels 8*sub .. 8*sub+7
    int j0 = rowptr[d];
    int cnt = counts[d];
    float dd = dinv[d];

    float a0 = 0.f, a1 = 0.f, a2 = 0.f, a3 = 0.f;
    float a4 = 0.f, a5 = 0.f, a6 = 0.f, a7 = 0.f;
    const uint4 zero4 = make_uint4(0u, 0u, 0u, 0u);
    for (int t = 0; t < cnt; t += 16) {
        int e0 = t + h, e1 = t + 4 + h, e2 = t + 8 + h, e3 = t + 12 + h;
        // over-reads stay inside the CAP-padded bucket region; mask below
        int s0 = esrc[j0 + e0] & 0x1FFFF;
        int s1 = esrc[j0 + e1] & 0x1FFFF;
        int s2 = esrc[j0 + e2] & 0x1FFFF;
        int s3 = esrc[j0 + e3] & 0x1FFFF;
        uint4 w0 = ((const uint4*)(xlp + (size_t)s0 * HID))[sub];
        uint4 w1 = ((const uint4*)(xlp + (size_t)s1 * HID))[sub];
        uint4 w2 = ((const uint4*)(xlp + (size_t)s2 * HID))[sub];
        uint4 w3 = ((const uint4*)(xlp + (size_t)s3 * HID))[sub];
        if (e0 >= cnt) w0 = zero4;
        if (e1 >= cnt) w1 = zero4;
        if (e2 >= cnt) w2 = zero4;
        if (e3 >= cnt) w3 = zero4;
        a0 += (bf_lo(w0.x) + bf_lo(w1.x)) + (bf_lo(w2.x) + bf_lo(w3.x));
        a1 += (bf_hi(w0.x) + bf_hi(w1.x)) + (bf_hi(w2.x) + bf_hi(w3.x));
        a2 += (bf_lo(w0.y) + bf_lo(w1.y)) + (bf_lo(w2.y) + bf_lo(w3.y));
        a3 += (bf_hi(w0.y) + bf_hi(w1.y)) + (bf_hi(w2.y) + bf_hi(w3.y));
        a4 += (bf_lo(w0.z) + bf_lo(w1.z)) + (bf_lo(w2.z) + bf_lo(w3.z));
        a5 += (bf_hi(w0.z) + bf_hi(w1.z)) + (bf_hi(w2.z) + bf_hi(w3.z));
        a6 += (bf_lo(w0.w) + bf_lo(w1.w)) + (bf_lo(w2.w) + bf_lo(w3.w));
        a7 += (bf_hi(w0.w) + bf_hi(w1.w)) + (bf_hi(w2.w) + bf_hi(w3.w));
    }
    // combine the 4 h-subgroups (lanes sharing `sub`)
    a0 += __shfl_xor(a0, 8);  a0 += __shfl_xor(a0, 16);
    a1 += __shfl_xor(a1, 8);  a1 += __shfl_xor(a1, 16);
    a2 += __shfl_xor(a2, 8);  a2 += __shfl_xor(a2, 16);
    a3 += __shfl_xor(a3, 8);  a3 += __shfl_xor(a3, 16);
    a4 += __shfl_xor(a4, 8);  a4 += __shfl_xor(a4, 16);
    a5 += __shfl_xor(a5, 8);  a5 += __shfl_xor(a5, 16);
    a6 += __shfl_xor(a6, 8);  a6 += __shfl_xor(a6, 16);
    a7 += __shfl_xor(a7, 8);  a7 += __shfl_xor(a7, 16);

    uint4 wsv = ((const uint4*)(xlp + (size_t)d * HID))[sub];  // self-loop
    float4 bA = *(const float4*)&b1[8 * sub];
    float4 bB = *(const float4*)&b1[8 * sub + 4];
    float v0 = fmaxf(dd * (a0 + bf_lo(wsv.x)) + bA.x, 0.f);
    float v1 = fmaxf(dd * (a1 + bf_hi(wsv.x)) + bA.y, 0.f);
    float v2 = fmaxf(dd * (a2 + bf_lo(wsv.y)) + bA.z, 0.f);
    float v3 = fmaxf(dd * (a3 + bf_hi(wsv.y)) + bA.w, 0.f);
    float v4 = fmaxf(dd * (a4 + bf_lo(wsv.z)) + bB.x, 0.f);
    float v5 = fmaxf(dd * (a5 + bf_hi(wsv.z)) + bB.y, 0.f);
    float v6 = fmaxf(dd * (a6 + bf_lo(wsv.w)) + bB.z, 0.f);
    float v7 = fmaxf(dd * (a7 + bf_hi(wsv.w)) + bB.w, 0.f);
    // group-private staging: h==0 lanes write all 64 channels;
    // same-wave write->read, SIMD program order (validated round 14)
    if (h == 0) {
        *(float4*)&sh[g][8 * sub]     = make_float4(v0, v1, v2, v3);
        *(float4*)&sh[g][8 * sub + 4] = make_float4(v4, v5, v6, v7);
    }

    int j = cl & 15, kh = cl >> 4;
    float acc = 0.f;
#pragma unroll 8
    for (int k = 0; k < 32; ++k) {
        int kk = kh * 32 + k;
        acc += sh[g][kk] * sW2[kk * OUT_CH + j];
    }
    acc += __shfl_xor(acc, 16);  // combine k-halves
    if (cl < 16)
        hlp[(size_t)d * OUT_CH + j] = __float2bfloat16(dd * acc);
}

// ---------------- layer 2 aggregation, uint2 pair-gathers (r16 verbatim) ----
// 8-lane group per dst. h = cl>>2 picks 1 of 2 edges; sub = cl&3 picks an
// 8B slice (4 ch) of the 32B hlp row.

__global__ __launch_bounds__(256) void k_agg2(const int* __restrict__ rowptr,
                                              const int* __restrict__ counts,
                                              const int* __restrict__ esrc,
                                              const float* __restrict__ dinv,
                                              const __hip_bfloat16* __restrict__ hlp,
                                              const float* __restrict__ b,
                                              float* __restrict__ out, int n) {
    int d = blockIdx.x * 32 + (threadIdx.x >> 3);
    if (d >= n) return;
    int cl = threadIdx.x & 7;
    int h = cl >> 2;     // edge slot within pair
    int sub = cl & 3;    // 8B slice -> channels 4*sub .. 4*sub+3
    int j0 = rowptr[d];
    int cnt = counts[d];
    float dd = dinv[d];

    float a0 = 0.f, a1 = 0.f, a2 = 0.f, a3 = 0.f;
    const uint2 zero2 = make_uint2(0u, 0u);
    for (int t = 0; t < cnt; t += 8) {
        int e0 = t + h, e1 = t + 2 + h, e2 = t + 4 + h, e3 = t + 6 + h;
        int s0 = esrc[j0 + e0] & 0x1FFFF;
        int s1 = esrc[j0 + e1] & 0x1FFFF;
        int s2 = esrc[j0 + e2] & 0x1FFFF;
        int s3 = esrc[j0 + e3] & 0x1FFFF;
        uint2 w0 = ((const uint2*)(hlp + (size_t)s0 * OUT_CH))[sub];
        uint2 w1 = ((const uint2*)(hlp + (size_t)s1 * OUT_CH))[sub];
        uint2 w2 = ((const uint2*)(hlp + (size_t)s2 * OUT_CH))[sub];
        uint2 w3 = ((const uint2*)(hlp + (size_t)s3 * OUT_CH))[sub];
        if (e0 >= cnt) w0 = zero2;
        if (e1 >= cnt) w1 = zero2;
        if (e2 >= cnt) w2 = zero2;
        if (e3 >= cnt) w3 = zero2;
        a0 += (bf_lo(w0.x) + bf_lo(w1.x)) + (bf_lo(w2.x) + bf_lo(w3.x));
        a1 += (bf_hi(w0.x) + bf_hi(w1.x)) + (bf_hi(w2.x) + bf_hi(w3.x));
        a2 += (bf_lo(w0.y) + bf_lo(w1.y)) + (bf_lo(w2.y) + bf_lo(w3.y));
        a3 += (bf_hi(w0.y) + bf_hi(w1.y)) + (bf_hi(w2.y) + bf_hi(w3.y));
    }
    // combine the 2 h-subgroups (lane ^ 4 stays within the 8-lane group)
    a0 += __shfl_xor(a0, 4);
    a1 += __shfl_xor(a1, 4);
    a2 += __shfl_xor(a2, 4);
    a3 += __shfl_xor(a3, 4);

    uint2 ws = ((const uint2*)(hlp + (size_t)d * OUT_CH))[sub];  // self-loop
    float4 bv = *(const float4*)&b[4 * sub];
    float v0 = dd * (a0 + bf_lo(ws.x)) + bv.x;
    float v1 = dd * (a1 + bf_hi(ws.x)) + bv.y;
    float v2 = dd * (a2 + bf_lo(ws.y)) + bv.z;
    float v3 = dd * (a3 + bf_hi(ws.y)) + bv.w;
    if (h == 0)
        ((float4*)(out + (size_t)d * OUT_CH))[sub] = make_float4(v0, v1, v2, v3);
}

extern "C" void kernel_launch(void* const* d_in, const int* in_sizes, int n_in,
                              void* d_out, int out_size, void* d_ws, size_t ws_size,
                              hipStream_t stream) {
    const float* x  = (const float*)d_in[0];
    const int* ei   = (const int*)d_in[1];   // int32 from harness
    const float* W1 = (const float*)d_in[2];
    const float* b1 = (const float*)d_in[3];
    const float* W2 = (const float*)d_in[4];
    const float* b2 = (const float*)d_in[5];
    float* out = (float*)d_out;

    const int n = in_sizes[0] / IN_CH;      // 100000
    const int E = in_sizes[1] / 2;          // 1600000
    const int nb = (n + G_SZ - 1) >> G_SH;  // 782 buckets
    const int nchunk = (E + CHUNK - 1) / CHUNK;  // 391 blocks

    int* rowptr  = (int*)d_ws;
    int* counts  = rowptr + n;
    int* bcursor = counts + n;
    unsigned short* wtbf = (unsigned short*)(bcursor + 1024);  // 8192 shorts
    int* packed  = (int*)(wtbf + 8192);
    float* dinv  = (float*)(packed + (size_t)nb * CAP);
    __hip_bfloat16* xlp = (__hip_bfloat16*)(dinv + n);          // n*64 bf16 (16B-aligned)
    __hip_bfloat16* hlp = xlp + (size_t)n * HID;                // n*16 bf16 (separate)

    // setup + CSR build (k_bucket frozen at round-11 version)
    k_setup<<<(IN_CH * HID + 255) / 256, 256, 0, stream>>>(bcursor, nb, W1, wtbf);
    k_bucket<<<nchunk, 256, 0, stream>>>(ei, bcursor, packed, E, nb);
    k_sortbkt<<<nb, 256, 0, stream>>>(bcursor, packed, rowptr, counts, dinv, n);

    // layer 1 (+ fused layer-2 transform)
    k_gemm1<<<(n + 63) / 64, 256, 0, stream>>>(x, wtbf, dinv, xlp, n);
    k_agg1f<<<(n + 7) / 8, 256, 0, stream>>>(rowptr, counts, packed, dinv, xlp, b1, W2, hlp, n);

    // layer 2 aggregation
    k_agg2<<<(n + 31) / 32, 256, 0, stream>>>(rowptr, counts, packed, dinv, hlp, b2, out, n);
}